// Round 5
// baseline (515.286 us; speedup 1.0000x reference)
//
#include <hip/hip_runtime.h>

typedef unsigned short u16;
typedef __bf16  bfrag  __attribute__((ext_vector_type(8)));   // MFMA A/B operand (4 VGPRs)
typedef float   f32x4  __attribute__((ext_vector_type(4)));   // MFMA C/D operand
typedef u16     u16x8  __attribute__((ext_vector_type(8)));
typedef u16     u16x4  __attribute__((ext_vector_type(4)));

__device__ __forceinline__ float bf2f(u16 u) {
    unsigned v = ((unsigned)u) << 16;
    return __builtin_bit_cast(float, v);
}
__device__ __forceinline__ u16 f2bf(float f) {   // round-to-nearest-even
    unsigned x = __builtin_bit_cast(unsigned, f);
    unsigned r = (x + 0x7fffu + ((x >> 16) & 1u)) >> 16;
    return (u16)r;
}
__device__ __forceinline__ void g2l16(const u16* g, u16* l) {
    // 16B per lane -> lds_base + lane*16 (wave-uniform LDS base)
    __builtin_amdgcn_global_load_lds((__attribute__((address_space(1))) void*)g,
                                     (__attribute__((address_space(3))) void*)l, 16, 0, 0);
}
__device__ __forceinline__ float gelu_tanh(float x) {
    // 0.5x(1+tanh(c)) == x * sigmoid(2c)
    float c = 1.5957691216057308f * (x + 0.044715f * x * x * x);
    return x * __frcp_rn(1.0f + __expf(-c));
}

// Period-8 LDS swizzle (bank-conflict-free fragment reads):
#define SWZ(lane)  ((((lane) & 3) ^ (((lane) >> 3) & 3)) * 8)
#define RSWZ(quad, l15)  ((((quad) ^ (((l15) >> 1) & 3))) * 8)
#define BK 32

// ---------------- weight transposes + LN1 fused in ONE kernel ---------------
// blocks [0,16384): Wt[c][r] = bf16(W[r][c]); blocks [16384,20480): ln1 rows.
__global__ __launch_bounds__(256) void wtln(
        const float* __restrict__ Wq, const float* __restrict__ Wk,
        const float* __restrict__ Wv, const float* __restrict__ Wo,
        const float* __restrict__ W1, const float* __restrict__ W2,
        const float* __restrict__ W3,
        u16* __restrict__ WqkvT, u16* __restrict__ WoT,
        u16* __restrict__ W12T, u16* __restrict__ W3T,
        const float* __restrict__ x, const float* __restrict__ ln1_s,
        const float* __restrict__ ln1_b, u16* __restrict__ xn1) {
    __shared__ float tile[32][33];
    int blk = blockIdx.x;
    if (blk >= 16384) {
        // ---- LayerNorm path ----
        int row = blk - 16384, t = threadIdx.x;
        float4 v = ((const float4*)(x + (size_t)row * 1024))[t];
        float sum = v.x + v.y + v.z + v.w;
        float sq  = v.x * v.x + v.y * v.y + v.z * v.z + v.w * v.w;
#pragma unroll
        for (int off = 1; off < 64; off <<= 1) {
            sum += __shfl_xor(sum, off);
            sq  += __shfl_xor(sq,  off);
        }
        float* s1 = &tile[0][0];
        float* s2 = &tile[0][8];
        int wave = t >> 6;
        if ((t & 63) == 0) { s1[wave] = sum; s2[wave] = sq; }
        __syncthreads();
        sum = s1[0] + s1[1] + s1[2] + s1[3];
        sq  = s2[0] + s2[1] + s2[2] + s2[3];
        float mean = sum * (1.0f / 1024.0f);
        float var  = sq  * (1.0f / 1024.0f) - mean * mean;
        float inv  = rsqrtf(var + 1e-6f);
        float4 sc = ((const float4*)ln1_s)[t], bb = ((const float4*)ln1_b)[t];
        u16x4 o;
        o[0] = f2bf((v.x - mean) * inv * sc.x + bb.x);
        o[1] = f2bf((v.y - mean) * inv * sc.y + bb.y);
        o[2] = f2bf((v.z - mean) * inv * sc.z + bb.z);
        o[3] = f2bf((v.w - mean) * inv * sc.w + bb.w);
        *(u16x4*)&xn1[(size_t)row * 1024 + t * 4] = o;
        return;
    }
    // ---- transpose path ----
    const float* W; u16* Wt; int R, C, local;
    if (blk < 3072) {
        int w = blk >> 10; local = blk & 1023;
        W = (w == 0) ? Wq : (w == 1) ? Wk : Wv;
        Wt = WqkvT + (size_t)w * 1024 * 1024; R = 1024; C = 1024;
    } else if (blk < 4096) { W = Wo; Wt = WoT; R = 1024; C = 1024; local = blk - 3072; }
    else if (blk < 8192)   { W = W1; Wt = W12T; R = 1024; C = 4096; local = blk - 4096; }
    else if (blk < 12288)  { W = W2; Wt = W12T + (size_t)4096 * 1024; R = 1024; C = 4096; local = blk - 8192; }
    else                   { W = W3; Wt = W3T; R = 4096; C = 1024; local = blk - 12288; }
    int tiles_x = C >> 5;
    int c0 = (local % tiles_x) * 32, r0 = (local / tiles_x) * 32;
    int tx = threadIdx.x & 31, ty = threadIdx.x >> 5;
#pragma unroll
    for (int i = 0; i < 32; i += 8)
        tile[ty + i][tx] = W[(size_t)(r0 + ty + i) * C + c0 + tx];
    __syncthreads();
#pragma unroll
    for (int i = 0; i < 32; i += 8)
        Wt[(size_t)(c0 + ty + i) * R + r0 + tx] = f2bf(tile[tx][ty + i]);
}

// ---------------- LayerNorm over D=1024, fp32 in -> bf16 out (ln2) ----------
__global__ __launch_bounds__(256) void ln1024(const float* __restrict__ x,
                                              const float* __restrict__ s,
                                              const float* __restrict__ bi,
                                              u16* __restrict__ out) {
    int row = blockIdx.x, t = threadIdx.x;
    float4 v = ((const float4*)(x + (size_t)row * 1024))[t];
    float sum = v.x + v.y + v.z + v.w;
    float sq  = v.x * v.x + v.y * v.y + v.z * v.z + v.w * v.w;
#pragma unroll
    for (int off = 1; off < 64; off <<= 1) {
        sum += __shfl_xor(sum, off);
        sq  += __shfl_xor(sq,  off);
    }
    __shared__ float s1[4], s2[4];
    int wave = t >> 6;
    if ((t & 63) == 0) { s1[wave] = sum; s2[wave] = sq; }
    __syncthreads();
    sum = s1[0] + s1[1] + s1[2] + s1[3];
    sq  = s2[0] + s2[1] + s2[2] + s2[3];
    float mean = sum * (1.0f / 1024.0f);
    float var  = sq  * (1.0f / 1024.0f) - mean * mean;
    float inv  = rsqrtf(var + 1e-6f);
    float4 sc = ((const float4*)s)[t], bb = ((const float4*)bi)[t];
    u16x4 o;
    o[0] = f2bf((v.x - mean) * inv * sc.x + bb.x);
    o[1] = f2bf((v.y - mean) * inv * sc.y + bb.y);
    o[2] = f2bf((v.z - mean) * inv * sc.z + bb.z);
    o[3] = f2bf((v.w - mean) * inv * sc.w + bb.w);
    *(u16x4*)&out[(size_t)row * 1024 + t * 4] = o;
}

// ---- gemm2: 128-thread / 2-wave blocks, wave tile 128x64 (8x4 frags) -------
// Block tile 128x128. acc=128 AGPR/wave: same 2-waves/SIMD occupancy bucket as
// the 4x4 config, but LDS bytes/MFMA drop 768->640 and per-wave barrier
// overhead halves. EPI 0: bf16 split-K partial | 4: QKV + per-head LN.
template <int EPI>
__global__ __launch_bounds__(128) void gemm2(const u16* __restrict__ A,
                                             const u16* __restrict__ Bt,
                                             const float* __restrict__ bias,
                                             const float* __restrict__ bias2,
                                             const float* __restrict__ bias3,
                                             const float* __restrict__ qn_s,
                                             const float* __restrict__ qn_b,
                                             const float* __restrict__ kn_s,
                                             const float* __restrict__ kn_b,
                                             u16* __restrict__ p0,
                                             u16* __restrict__ p1,
                                             u16* __restrict__ p2,
                                             u16* __restrict__ p3,
                                             int M, int N, int K, int Klen) {
    __shared__ u16 As[128 * BK];
    __shared__ u16 Bs[128 * BK];
    int tid = threadIdx.x, wave = tid >> 6, lane = tid & 63;
    int quad = lane >> 4, l15 = lane & 15;
    int row0 = blockIdx.y * 128, col0 = blockIdx.x * 128;
    int kz = blockIdx.z;
    int swz = SWZ(lane);
    int rswz = RSWZ(quad, l15);

    f32x4 acc[8][4] = {};

    const u16* gA = A  + (size_t)(row0 + wave * 64 + (lane >> 2)) * K + kz * Klen + swz;
    const u16* gB = Bt + (size_t)(col0 + wave * 64 + (lane >> 2)) * K + kz * Klen + swz;
    u16* lA = &As[wave * 64 * BK];
    u16* lB = &Bs[wave * 64 * BK];

    for (int k0 = 0; k0 < Klen; k0 += BK) {
        __syncthreads();
#pragma unroll
        for (int j = 0; j < 4; j++) {
            g2l16(gA + k0 + j * 16 * K, lA + j * 16 * BK);
            g2l16(gB + k0 + j * 16 * K, lB + j * 16 * BK);
        }
        __syncthreads();
        bfrag af[8], bf[4];
#pragma unroll
        for (int mi = 0; mi < 8; mi++)
            af[mi] = *(const bfrag*)&As[(mi * 16 + l15) * BK + rswz];
#pragma unroll
        for (int ni = 0; ni < 4; ni++)
            bf[ni] = *(const bfrag*)&Bs[(wave * 64 + ni * 16 + l15) * BK + rswz];
#pragma unroll
        for (int mi = 0; mi < 8; mi++)
#pragma unroll
            for (int ni = 0; ni < 4; ni++)
                acc[mi][ni] = __builtin_amdgcn_mfma_f32_16x16x32_bf16(
                    af[mi], bf[ni], acc[mi][ni], 0, 0, 0);
    }

    if (EPI == 0) {
        // split-K bf16 partial store
        u16* P = (kz == 0) ? p0 : (kz == 1) ? p1 : (kz == 2) ? p2 : p3;
#pragma unroll
        for (int mi = 0; mi < 8; mi++) {
            int rbase = row0 + mi * 16 + quad * 4;
#pragma unroll
            for (int r = 0; r < 4; r++)
#pragma unroll
                for (int ni = 0; ni < 4; ni++)
                    P[(size_t)(rbase + r) * N + col0 + wave * 64 + ni * 16 + l15] =
                        f2bf(acc[mi][ni][r]);
        }
    } else {
        // QKV epilogue: wave's 64 cols = one head; LN over head dim for q/k
        int cbase = col0 + wave * 64;
        int z = cbase >> 10;              // 0=q, 1=k, 2=v
        int hd = (cbase >> 6) & 15;
        const float* bp = (z == 0) ? bias : (z == 1) ? bias2 : bias3;
        float post = (z == 0) ? 0.125f : 1.0f;
        float bv[4], sn[4], bn[4];
#pragma unroll
        for (int ni = 0; ni < 4; ni++)
            bv[ni] = bp[(cbase & 1023) + ni * 16 + l15];
        if (z < 2) {
            const float* ns = (z == 0) ? qn_s : kn_s;
            const float* nb = (z == 0) ? qn_b : kn_b;
#pragma unroll
            for (int ni = 0; ni < 4; ni++) {
                sn[ni] = ns[hd * 64 + ni * 16 + l15];
                bn[ni] = nb[hd * 64 + ni * 16 + l15];
            }
        }
        u16* Cout = p0;
#pragma unroll
        for (int mi = 0; mi < 8; mi++) {
            int rbase = row0 + mi * 16 + quad * 4;
#pragma unroll
            for (int r = 0; r < 4; r++) {
                float v0 = acc[mi][0][r] + bv[0];
                float v1 = acc[mi][1][r] + bv[1];
                float v2 = acc[mi][2][r] + bv[2];
                float v3 = acc[mi][3][r] + bv[3];
                size_t rb = (size_t)(rbase + r) * N + cbase;
                if (z == 2) {
                    Cout[rb + 0 * 16 + l15] = f2bf(v0);
                    Cout[rb + 1 * 16 + l15] = f2bf(v1);
                    Cout[rb + 2 * 16 + l15] = f2bf(v2);
                    Cout[rb + 3 * 16 + l15] = f2bf(v3);
                } else {
                    float s  = v0 + v1 + v2 + v3;
                    float sq = v0 * v0 + v1 * v1 + v2 * v2 + v3 * v3;
#pragma unroll
                    for (int m = 1; m < 16; m <<= 1) {
                        s  += __shfl_xor(s,  m);
                        sq += __shfl_xor(sq, m);
                    }
                    float mean = s * (1.0f / 64.0f);
                    float var  = sq * (1.0f / 64.0f) - mean * mean;
                    float inv  = rsqrtf(var + 1e-6f);
                    Cout[rb + 0 * 16 + l15] = f2bf(((v0 - mean) * inv * sn[0] + bn[0]) * post);
                    Cout[rb + 1 * 16 + l15] = f2bf(((v1 - mean) * inv * sn[1] + bn[1]) * post);
                    Cout[rb + 2 * 16 + l15] = f2bf(((v2 - mean) * inv * sn[2] + bn[2]) * post);
                    Cout[rb + 3 * 16 + l15] = f2bf(((v3 - mean) * inv * sn[3] + bn[3]) * post);
                }
            }
        }
    }
}

// ---------------- GEMM (4-wave, 64x64 wave tile) — Wo path ------------------
// EPI 2: fp32 = acc + bias + res
template <int EPI, int BN_>
__global__ __launch_bounds__(256) void gemm_bt(const u16* __restrict__ A,
                                               const u16* __restrict__ Bt,
                                               const float* __restrict__ bias,
                                               const float* __restrict__ res,
                                               void* __restrict__ Cout,
                                               int M, int N, int K) {
    __shared__ u16 As[128 * BK];
    __shared__ u16 Bs[BN_ * BK];
    constexpr int MI = (BN_ == 128) ? 4 : 2;
    constexpr int NI = 4;
    int tid = threadIdx.x, wave = tid >> 6, lane = tid & 63;
    int quad = lane >> 4, l15 = lane & 15;
    int row0 = blockIdx.y * 128, col0 = blockIdx.x * BN_;
    int wr = (BN_ == 128) ? (wave >> 1) * 64 : wave * 32;
    int wc = (BN_ == 128) ? (wave & 1) * 64 : 0;
    int swz = SWZ(lane);
    int rswz = RSWZ(quad, l15);

    f32x4 acc[MI][NI] = {};

    const u16* gA = A + (size_t)(row0 + wave * 32 + (lane >> 2)) * K + swz;
    u16* lA = &As[wave * 32 * BK];
    const u16* gB;
    u16* lB;
    if (BN_ == 128) { gB = Bt + (size_t)(col0 + wave * 32 + (lane >> 2)) * K + swz; lB = &Bs[wave * 32 * BK]; }
    else            { gB = Bt + (size_t)(col0 + wave * 16 + (lane >> 2)) * K + swz; lB = &Bs[wave * 16 * BK]; }

    for (int k0 = 0; k0 < K; k0 += BK) {
        __syncthreads();
        g2l16(gA + k0,          lA);
        g2l16(gA + k0 + 16 * K, lA + 16 * BK);
        if (BN_ == 128) {
            g2l16(gB + k0,          lB);
            g2l16(gB + k0 + 16 * K, lB + 16 * BK);
        } else {
            g2l16(gB + k0, lB);
        }
        __syncthreads();
        bfrag af[MI], bf[NI];
#pragma unroll
        for (int mi = 0; mi < MI; mi++)
            af[mi] = *(const bfrag*)&As[(wr + mi * 16 + l15) * BK + rswz];
#pragma unroll
        for (int ni = 0; ni < NI; ni++)
            bf[ni] = *(const bfrag*)&Bs[(wc + ni * 16 + l15) * BK + rswz];
#pragma unroll
        for (int mi = 0; mi < MI; mi++)
#pragma unroll
            for (int ni = 0; ni < NI; ni++)
                acc[mi][ni] = __builtin_amdgcn_mfma_f32_16x16x32_bf16(
                    af[mi], bf[ni], acc[mi][ni], 0, 0, 0);
    }

    float bv[NI];
    int cols[NI];
#pragma unroll
    for (int ni = 0; ni < NI; ni++) {
        cols[ni] = col0 + wc + ni * 16 + l15;
        bv[ni]   = bias[cols[ni]];
    }
#pragma unroll
    for (int mi = 0; mi < MI; mi++) {
        int rbase = row0 + wr + mi * 16 + quad * 4;
#pragma unroll
        for (int r = 0; r < 4; r++) {
            int row = rbase + r;
#pragma unroll
            for (int ni = 0; ni < NI; ni++) {
                float val = acc[mi][ni][r] + bv[ni];
                size_t idx = (size_t)row * N + cols[ni];
                ((float*)Cout)[idx] = val + res[idx];
            }
        }
    }
}

// ---------------- fused GeGLU FFN GEMM: H = (A@W1+b1) * gelu(A@W2+b2) -------
__global__ __launch_bounds__(256, 2) void gemm_w12(const u16* __restrict__ A,
                                                   const u16* __restrict__ W12T,
                                                   const float* __restrict__ b1,
                                                   const float* __restrict__ b2,
                                                   u16* __restrict__ H) {
    __shared__ u16 As[128 * BK];
    __shared__ u16 B1s[128 * BK];
    __shared__ u16 B2s[128 * BK];
    int tid = threadIdx.x, wave = tid >> 6, lane = tid & 63;
    int quad = lane >> 4, l15 = lane & 15;
    int row0 = blockIdx.y * 128, col0 = blockIdx.x * 128;
    int wr = (wave >> 1) * 64, wc = (wave & 1) * 64;
    int swz = SWZ(lane);
    int rswz = RSWZ(quad, l15);

    f32x4 acc1[4][4] = {}, acc2[4][4] = {};

    const u16* gA  = A    + (size_t)(row0 + wave * 32 + (lane >> 2)) * 1024 + swz;
    const u16* gB1 = W12T + (size_t)(col0 + wave * 32 + (lane >> 2)) * 1024 + swz;
    const u16* gB2 = gB1  + (size_t)4096 * 1024;
    u16* lA  = &As [wave * 32 * BK];
    u16* lB1 = &B1s[wave * 32 * BK];
    u16* lB2 = &B2s[wave * 32 * BK];

    for (int k0 = 0; k0 < 1024; k0 += BK) {
        __syncthreads();
        g2l16(gA  + k0,             lA);
        g2l16(gA  + k0 + 16 * 1024, lA  + 16 * BK);
        g2l16(gB1 + k0,             lB1);
        g2l16(gB1 + k0 + 16 * 1024, lB1 + 16 * BK);
        g2l16(gB2 + k0,             lB2);
        g2l16(gB2 + k0 + 16 * 1024, lB2 + 16 * BK);
        __syncthreads();
        bfrag af[4], b1f[4], b2f[4];
#pragma unroll
        for (int mi = 0; mi < 4; mi++)
            af[mi] = *(const bfrag*)&As[(wr + mi * 16 + l15) * BK + rswz];
#pragma unroll
        for (int ni = 0; ni < 4; ni++) {
            b1f[ni] = *(const bfrag*)&B1s[(wc + ni * 16 + l15) * BK + rswz];
            b2f[ni] = *(const bfrag*)&B2s[(wc + ni * 16 + l15) * BK + rswz];
        }
#pragma unroll
        for (int mi = 0; mi < 4; mi++)
#pragma unroll
            for (int ni = 0; ni < 4; ni++) {
                acc1[mi][ni] = __builtin_amdgcn_mfma_f32_16x16x32_bf16(
                    af[mi], b1f[ni], acc1[mi][ni], 0, 0, 0);
                acc2[mi][ni] = __builtin_amdgcn_mfma_f32_16x16x32_bf16(
                    af[mi], b2f[ni], acc2[mi][ni], 0, 0, 0);
            }
    }

    float bv1[4], bv2[4];
    int cols[4];
#pragma unroll
    for (int ni = 0; ni < 4; ni++) {
        cols[ni] = col0 + wc + ni * 16 + l15;
        bv1[ni] = b1[cols[ni]];
        bv2[ni] = b2[cols[ni]];
    }
#pragma unroll
    for (int mi = 0; mi < 4; mi++) {
        int rbase = row0 + wr + mi * 16 + quad * 4;
#pragma unroll
        for (int r = 0; r < 4; r++) {
#pragma unroll
            for (int ni = 0; ni < 4; ni++) {
                float x1 = acc1[mi][ni][r] + bv1[ni];
                float x2 = acc2[mi][ni][r] + bv2[ni];
                H[(size_t)(rbase + r) * 4096 + cols[ni]] = f2bf(x1 * gelu_tanh(x2));
            }
        }
    }
}

// ---------------- reduce: out = xmid + b3 + sum of 4 bf16 partials ----------
__global__ __launch_bounds__(256) void reduce4(const u16* __restrict__ p0,
                                               const u16* __restrict__ p1,
                                               const u16* __restrict__ p2,
                                               const u16* __restrict__ p3,
                                               const float* __restrict__ xmid,
                                               const float* __restrict__ b3,
                                               float* __restrict__ out) {
    size_t i = ((size_t)blockIdx.x * 256 + threadIdx.x) * 4;
    float4 xm = *(const float4*)&xmid[i];
    float4 bb = *(const float4*)&b3[i & 1023];
    u16x4 a0 = *(const u16x4*)&p0[i];
    u16x4 a1 = *(const u16x4*)&p1[i];
    u16x4 a2 = *(const u16x4*)&p2[i];
    u16x4 a3 = *(const u16x4*)&p3[i];
    float4 o;
    o.x = xm.x + bb.x + bf2f(a0[0]) + bf2f(a1[0]) + bf2f(a2[0]) + bf2f(a3[0]);
    o.y = xm.y + bb.y + bf2f(a0[1]) + bf2f(a1[1]) + bf2f(a2[1]) + bf2f(a3[1]);
    o.z = xm.z + bb.z + bf2f(a0[2]) + bf2f(a1[2]) + bf2f(a2[2]) + bf2f(a3[2]);
    o.w = xm.w + bb.w + bf2f(a0[3]) + bf2f(a1[3]) + bf2f(a2[3]) + bf2f(a3[3]);
    *(float4*)&out[i] = o;
}

// ---------------- Flash attention on packed qkv [4096][3072] ----------------
#define LP 72
__global__ __launch_bounds__(256) void flash(const u16* __restrict__ qkv,
                                             u16* __restrict__ o) {
    int qt = blockIdx.x, h = blockIdx.y, b = blockIdx.z;
    int tid = threadIdx.x, wave = tid >> 6, lane = tid & 63;
    int quad = lane >> 4, l15 = lane & 15;

    __shared__ u16 Qs[128 * LP];
    __shared__ u16 Ks[64 * LP];
    __shared__ u16 Vt[64 * LP];   // [d][key]
    __shared__ u16 Ps[128 * LP];

    {
        int row = tid >> 1, half = tid & 1;
        const u16* src = qkv + (size_t)(b * 1024 + qt * 128 + row) * 3072 + h * 64 + half * 32;
        u16* dst = &Qs[row * LP + half * 32];
#pragma unroll
        for (int i = 0; i < 4; i++)
            ((u16x8*)dst)[i] = ((const u16x8*)src)[i];
    }

    f32x4 accO[2][4] = {};
    float m_run[2][4], l_run[2][4];
#pragma unroll
    for (int rt = 0; rt < 2; rt++)
#pragma unroll
        for (int r = 0; r < 4; r++) { m_run[rt][r] = -1e30f; l_run[rt][r] = 0.0f; }

    for (int kt = 0; kt < 16; kt++) {
        __syncthreads();
        {
            int row = tid >> 2, seg = tid & 3;
            size_t gb = (size_t)(b * 1024 + kt * 64 + row) * 3072 + h * 64;
            const u16* ksrc = qkv + gb + 1024 + seg * 16;
            *(u16x8*)&Ks[row * LP + seg * 16]     = *(const u16x8*)ksrc;
            *(u16x8*)&Ks[row * LP + seg * 16 + 8] = *(const u16x8*)(ksrc + 8);
            const u16* vsrc = qkv + gb + 2048 + seg * 16;
            u16x8 v0 = *(const u16x8*)vsrc, v1 = *(const u16x8*)(vsrc + 8);
#pragma unroll
            for (int j = 0; j < 8; j++) Vt[(seg * 16 + j) * LP + row]     = v0[j];
#pragma unroll
            for (int j = 0; j < 8; j++) Vt[(seg * 16 + 8 + j) * LP + row] = v1[j];
        }
        __syncthreads();

        f32x4 accS[2][4] = {};
#pragma unroll
        for (int kk = 0; kk < 2; kk++) {
            bfrag aq[2];
#pragma unroll
            for (int rt = 0; rt < 2; rt++)
                aq[rt] = *(const bfrag*)&Qs[(wave * 32 + rt * 16 + l15) * LP + kk * 32 + quad * 8];
#pragma unroll
            for (int ct = 0; ct < 4; ct++) {
                bfrag bk = *(const bfrag*)&Ks[(ct * 16 + l15) * LP + kk * 32 + quad * 8];
                accS[0][ct] = __builtin_amdgcn_mfma_f32_16x16x32_bf16(aq[0], bk, accS[0][ct], 0, 0, 0);
                accS[1][ct] = __builtin_amdgcn_mfma_f32_16x16x32_bf16(aq[1], bk, accS[1][ct], 0, 0, 0);
            }
        }

#pragma unroll
        for (int rt = 0; rt < 2; rt++) {
#pragma unroll
            for (int r = 0; r < 4; r++) {
                float tmax = accS[rt][0][r];
#pragma unroll
                for (int ct = 1; ct < 4; ct++) tmax = fmaxf(tmax, accS[rt][ct][r]);
#pragma unroll
                for (int m = 1; m < 16; m <<= 1) tmax = fmaxf(tmax, __shfl_xor(tmax, m));
                float mnew  = fmaxf(m_run[rt][r], tmax);
                float alpha = __expf(m_run[rt][r] - mnew);
                float lsum = 0.0f;
                float p[4];
#pragma unroll
                for (int ct = 0; ct < 4; ct++) {
                    p[ct] = __expf(accS[rt][ct][r] - mnew);
                    lsum += p[ct];
                }
#pragma unroll
                for (int m = 1; m < 16; m <<= 1) lsum += __shfl_xor(lsum, m);
                l_run[rt][r] = l_run[rt][r] * alpha + lsum;
                m_run[rt][r] = mnew;
#pragma unroll
                for (int oc = 0; oc < 4; oc++) accO[rt][oc][r] *= alpha;
                int prow = wave * 32 + rt * 16 + quad * 4 + r;
#pragma unroll
                for (int ct = 0; ct < 4; ct++)
                    Ps[prow * LP + ct * 16 + l15] = f2bf(p[ct]);
            }
        }

#pragma unroll
        for (int kk = 0; kk < 2; kk++) {
            bfrag ap[2];
#pragma unroll
            for (int rt = 0; rt < 2; rt++)
                ap[rt] = *(const bfrag*)&Ps[(wave * 32 + rt * 16 + l15) * LP + kk * 32 + quad * 8];
#pragma unroll
            for (int oc = 0; oc < 4; oc++) {
                bfrag bv = *(const bfrag*)&Vt[(oc * 16 + l15) * LP + kk * 32 + quad * 8];
                accO[0][oc] = __builtin_amdgcn_mfma_f32_16x16x32_bf16(ap[0], bv, accO[0][oc], 0, 0, 0);
                accO[1][oc] = __builtin_amdgcn_mfma_f32_16x16x32_bf16(ap[1], bv, accO[1][oc], 0, 0, 0);
            }
        }
    }

#pragma unroll
    for (int rt = 0; rt < 2; rt++) {
#pragma unroll
        for (int r = 0; r < 4; r++) {
            int srow = qt * 128 + wave * 32 + rt * 16 + quad * 4 + r;
            float linv = 1.0f / l_run[rt][r];
#pragma unroll
            for (int oc = 0; oc < 4; oc++)
                o[(size_t)(b * 1024 + srow) * 1024 + h * 64 + oc * 16 + l15] =
                    f2bf(accO[rt][oc][r] * linv);
        }
    }
}

// ---------------------------------------------------------------------------
extern "C" void kernel_launch(void* const* d_in, const int* in_sizes, int n_in,
                              void* d_out, int out_size, void* d_ws, size_t ws_size,
                              hipStream_t stream) {
    const float* x     = (const float*)d_in[0];
    const float* ln1_s = (const float*)d_in[2];
    const float* ln1_b = (const float*)d_in[3];
    const float* Wq = (const float*)d_in[4];  const float* bq = (const float*)d_in[5];
    const float* Wk = (const float*)d_in[6];  const float* bk = (const float*)d_in[7];
    const float* Wv = (const float*)d_in[8];  const float* bv = (const float*)d_in[9];
    const float* qn_s = (const float*)d_in[10]; const float* qn_b = (const float*)d_in[11];
    const float* kn_s = (const float*)d_in[12]; const float* kn_b = (const float*)d_in[13];
    const float* Wo = (const float*)d_in[14]; const float* bo = (const float*)d_in[15];
    const float* ln2_s = (const float*)d_in[16]; const float* ln2_b = (const float*)d_in[17];
    const float* W1 = (const float*)d_in[18]; const float* b1 = (const float*)d_in[19];
    const float* W2 = (const float*)d_in[20]; const float* b2 = (const float*)d_in[21];
    const float* W3 = (const float*)d_in[22]; const float* b3 = (const float*)d_in[23];
    float* out = (float*)d_out;

    char* ws = (char*)d_ws;
    const size_t MB = (size_t)1 << 20;
    u16* WqkvT = (u16*)(ws + 0);         // 0..6    dead after QKV; then p0 @0
    u16* WoT   = (u16*)(ws + 6 * MB);    // 6..8    dead after Wo
    u16* W12T  = (u16*)(ws + 8 * MB);    // 8..24   dead after W12; then p1/p2
    u16* W3T   = (u16*)(ws + 24 * MB);   // 24..32  dead after splitk
    u16* xn1   = (u16*)(ws + 32 * MB);   // 32..40  dead after QKV
    u16* attn  = (u16*)(ws + 32 * MB);   //   reuse: dead after Wo
    u16* xn2   = (u16*)(ws + 32 * MB);   //   reuse: dead after W12
    u16* qkv   = (u16*)(ws + 40 * MB);   // 40..64  dead after flash
    float* xmid = (float*)(ws + 40 * MB);//   reuse: 40..56, alive until reduce
    u16* p3    = (u16*)(ws + 56 * MB);   // 56..64
    u16* h     = (u16*)(ws + 64 * MB);   // 64..96  dead after splitk
    u16* p0    = (u16*)(ws + 0);
    u16* p1    = (u16*)(ws + 8 * MB);
    u16* p2    = (u16*)(ws + 16 * MB);
    // peak = 96 MB

    // weight transposes + ln1 fused
    wtln<<<20480, 256, 0, stream>>>(Wq, Wk, Wv, Wo, W1, W2, W3,
                                    WqkvT, WoT, W12T, W3T,
                                    x, ln1_s, ln1_b, xn1);

    // fused QKV + per-head QK-norm (2-wave blocks, 8x4 wave tile)
    gemm2<4><<<dim3(24, 32), 128, 0, stream>>>(
        xn1, WqkvT, bq, bk, bv, qn_s, qn_b, kn_s, kn_b,
        qkv, nullptr, nullptr, nullptr, 4096, 3072, 1024, 1024);

    flash<<<dim3(8, 16, 4), 256, 0, stream>>>(qkv, attn);

    // xmid = x + attn @ Wo + bo
    gemm_bt<2, 64><<<dim3(16, 32), 256, 0, stream>>>(
        attn, WoT, bo, x, xmid, 4096, 1024, 1024);

    ln1024<<<4096, 256, 0, stream>>>(xmid, ln2_s, ln2_b, xn2);

    // fused GeGLU FFN: h = (xn2@W1+b1) * gelu(xn2@W2+b2)
    gemm_w12<<<dim3(32, 32), 256, 0, stream>>>(xn2, W12T, b1, b2, h);

    // W3 split-K=4 partials (2-wave blocks, 8x4 wave tile)
    gemm2<0><<<dim3(8, 32, 4), 128, 0, stream>>>(
        h, W3T, nullptr, nullptr, nullptr, nullptr, nullptr, nullptr, nullptr,
        p0, p1, p2, p3, 4096, 1024, 4096, 1024);

    // out = xmid + b3 + sum(partials)
    reduce4<<<4096, 256, 0, stream>>>(p0, p1, p2, p3, xmid, b3, out);
}

// Round 6
// 435.294 us; speedup vs baseline: 1.1838x; 1.1838x over previous
//
#include <hip/hip_runtime.h>

typedef unsigned short u16;
typedef __bf16  bfrag  __attribute__((ext_vector_type(8)));   // MFMA A/B operand (4 VGPRs)
typedef float   f32x4  __attribute__((ext_vector_type(4)));   // MFMA C/D operand
typedef u16     u16x8  __attribute__((ext_vector_type(8)));
typedef u16     u16x4  __attribute__((ext_vector_type(4)));

__device__ __forceinline__ float bf2f(u16 u) {
    unsigned v = ((unsigned)u) << 16;
    return __builtin_bit_cast(float, v);
}
__device__ __forceinline__ u16 f2bf(float f) {   // round-to-nearest-even
    unsigned x = __builtin_bit_cast(unsigned, f);
    unsigned r = (x + 0x7fffu + ((x >> 16) & 1u)) >> 16;
    return (u16)r;
}
__device__ __forceinline__ void g2l16(const u16* g, u16* l) {
    // 16B per lane -> lds_base + lane*16 (wave-uniform LDS base)
    __builtin_amdgcn_global_load_lds((__attribute__((address_space(1))) void*)g,
                                     (__attribute__((address_space(3))) void*)l, 16, 0, 0);
}
__device__ __forceinline__ float gelu_tanh(float x) {
    // 0.5x(1+tanh(c)) == x * sigmoid(2c)
    float c = 1.5957691216057308f * (x + 0.044715f * x * x * x);
    return x * __frcp_rn(1.0f + __expf(-c));
}

// BK=64 LDS tiles: row = 128 B = 8 chunks of 16 B = exactly one 32-bank stripe.
// Swizzle phys_chunk = logical_chunk ^ (row & 7): each wave64 b128 frag read
// lands 8 lanes on each of the 8 bank groups -> structurally conflict-free.
// Staging source k-offset for lane l (covers row l>>3, phys chunk l&7):
#define SW64(l)   (((((l) & 7) ^ (((l) >> 3) & 7))) * 8)
// Fragment-read k-offset (row & 7 == l15 & 7 since row bases are 16-aligned):
#define RS64(kk, quad, l15)  (((((kk) * 4 + (quad)) ^ ((l15) & 7))) * 8)

// ---------------- weight transposes + LN1 fused in ONE kernel ---------------
// blocks [0,16384): Wt[c][r] = bf16(W[r][c]); blocks [16384,20480): ln1 rows.
__global__ __launch_bounds__(256) void wtln(
        const float* __restrict__ Wq, const float* __restrict__ Wk,
        const float* __restrict__ Wv, const float* __restrict__ Wo,
        const float* __restrict__ W1, const float* __restrict__ W2,
        const float* __restrict__ W3,
        u16* __restrict__ WqkvT, u16* __restrict__ WoT,
        u16* __restrict__ W12T, u16* __restrict__ W3T,
        const float* __restrict__ x, const float* __restrict__ ln1_s,
        const float* __restrict__ ln1_b, u16* __restrict__ xn1) {
    __shared__ float tile[32][33];
    int blk = blockIdx.x;
    if (blk >= 16384) {
        int row = blk - 16384, t = threadIdx.x;
        float4 v = ((const float4*)(x + (size_t)row * 1024))[t];
        float sum = v.x + v.y + v.z + v.w;
        float sq  = v.x * v.x + v.y * v.y + v.z * v.z + v.w * v.w;
#pragma unroll
        for (int off = 1; off < 64; off <<= 1) {
            sum += __shfl_xor(sum, off);
            sq  += __shfl_xor(sq,  off);
        }
        float* s1 = &tile[0][0];
        float* s2 = &tile[0][8];
        int wave = t >> 6;
        if ((t & 63) == 0) { s1[wave] = sum; s2[wave] = sq; }
        __syncthreads();
        sum = s1[0] + s1[1] + s1[2] + s1[3];
        sq  = s2[0] + s2[1] + s2[2] + s2[3];
        float mean = sum * (1.0f / 1024.0f);
        float var  = sq  * (1.0f / 1024.0f) - mean * mean;
        float inv  = rsqrtf(var + 1e-6f);
        float4 sc = ((const float4*)ln1_s)[t], bb = ((const float4*)ln1_b)[t];
        u16x4 o;
        o[0] = f2bf((v.x - mean) * inv * sc.x + bb.x);
        o[1] = f2bf((v.y - mean) * inv * sc.y + bb.y);
        o[2] = f2bf((v.z - mean) * inv * sc.z + bb.z);
        o[3] = f2bf((v.w - mean) * inv * sc.w + bb.w);
        *(u16x4*)&xn1[(size_t)row * 1024 + t * 4] = o;
        return;
    }
    const float* W; u16* Wt; int R, C, local;
    if (blk < 3072) {
        int w = blk >> 10; local = blk & 1023;
        W = (w == 0) ? Wq : (w == 1) ? Wk : Wv;
        Wt = WqkvT + (size_t)w * 1024 * 1024; R = 1024; C = 1024;
    } else if (blk < 4096) { W = Wo; Wt = WoT; R = 1024; C = 1024; local = blk - 3072; }
    else if (blk < 8192)   { W = W1; Wt = W12T; R = 1024; C = 4096; local = blk - 4096; }
    else if (blk < 12288)  { W = W2; Wt = W12T + (size_t)4096 * 1024; R = 1024; C = 4096; local = blk - 8192; }
    else                   { W = W3; Wt = W3T; R = 4096; C = 1024; local = blk - 12288; }
    int tiles_x = C >> 5;
    int c0 = (local % tiles_x) * 32, r0 = (local / tiles_x) * 32;
    int tx = threadIdx.x & 31, ty = threadIdx.x >> 5;
#pragma unroll
    for (int i = 0; i < 32; i += 8)
        tile[ty + i][tx] = W[(size_t)(r0 + ty + i) * C + c0 + tx];
    __syncthreads();
#pragma unroll
    for (int i = 0; i < 32; i += 8)
        Wt[(size_t)(c0 + ty + i) * R + r0 + tx] = f2bf(tile[tx][ty + i]);
}

// ---- gemm64: 4-wave 128x128 block tile, 64x64 wave tile, BK=64 -------------
// Halved barrier count vs BK=32 (the vmcnt(0)+s_barrier drain is the known
// ~20% stall of this structure). acc 64 AGPR + ~100 VGPR -> 3 waves/SIMD.
// EPI 0: bf16 partial store to o[kz] (split-K) | 4: QKV + per-head LN.
template <int EPI>
__global__ __launch_bounds__(256, 3) void gemm64(const u16* __restrict__ A,
                                                 const u16* __restrict__ Bt,
                                                 const float* __restrict__ bias,
                                                 const float* __restrict__ bias2,
                                                 const float* __restrict__ bias3,
                                                 const float* __restrict__ qn_s,
                                                 const float* __restrict__ qn_b,
                                                 const float* __restrict__ kn_s,
                                                 const float* __restrict__ kn_b,
                                                 u16* __restrict__ o0,
                                                 u16* __restrict__ o1,
                                                 u16* __restrict__ o2,
                                                 u16* __restrict__ o3,
                                                 int M, int N, int K, int Klen) {
    __shared__ u16 As[128 * 64];
    __shared__ u16 Bs[128 * 64];
    int tid = threadIdx.x, wave = tid >> 6, lane = tid & 63;
    int quad = lane >> 4, l15 = lane & 15;
    int row0 = blockIdx.y * 128, col0 = blockIdx.x * 128;
    int kz = blockIdx.z;
    int wr = (wave >> 1) * 64, wc = (wave & 1) * 64;
    int swz = SW64(lane);

    f32x4 acc[4][4] = {};

    const u16* gA = A  + (size_t)(row0 + wave * 32 + (lane >> 3)) * K + kz * Klen + swz;
    const u16* gB = Bt + (size_t)(col0 + wave * 32 + (lane >> 3)) * K + kz * Klen + swz;
    u16* lA = &As[wave * 32 * 64];
    u16* lB = &Bs[wave * 32 * 64];

    for (int k0 = 0; k0 < Klen; k0 += 64) {
        __syncthreads();
#pragma unroll
        for (int j = 0; j < 4; j++) {
            g2l16(gA + k0 + j * 8 * K, lA + j * 8 * 64);
            g2l16(gB + k0 + j * 8 * K, lB + j * 8 * 64);
        }
        __syncthreads();
#pragma unroll
        for (int kk = 0; kk < 2; kk++) {
            int rs = RS64(kk, quad, l15);
            bfrag af[4], bf[4];
#pragma unroll
            for (int mi = 0; mi < 4; mi++)
                af[mi] = *(const bfrag*)&As[(wr + mi * 16 + l15) * 64 + rs];
#pragma unroll
            for (int ni = 0; ni < 4; ni++)
                bf[ni] = *(const bfrag*)&Bs[(wc + ni * 16 + l15) * 64 + rs];
#pragma unroll
            for (int mi = 0; mi < 4; mi++)
#pragma unroll
                for (int ni = 0; ni < 4; ni++)
                    acc[mi][ni] = __builtin_amdgcn_mfma_f32_16x16x32_bf16(
                        af[mi], bf[ni], acc[mi][ni], 0, 0, 0);
        }
    }

    if (EPI == 0) {
        u16* P = (kz == 0) ? o0 : (kz == 1) ? o1 : (kz == 2) ? o2 : o3;
#pragma unroll
        for (int mi = 0; mi < 4; mi++) {
            int rbase = row0 + wr + mi * 16 + quad * 4;
#pragma unroll
            for (int r = 0; r < 4; r++)
#pragma unroll
                for (int ni = 0; ni < 4; ni++)
                    P[(size_t)(rbase + r) * N + col0 + wc + ni * 16 + l15] =
                        f2bf(acc[mi][ni][r]);
        }
    } else {
        // QKV epilogue: wave's 64 cols = one head; LN over head dim for q/k
        int cbase = col0 + wc;
        int z = cbase >> 10;              // 0=q, 1=k, 2=v
        int hd = (cbase >> 6) & 15;
        const float* bp = (z == 0) ? bias : (z == 1) ? bias2 : bias3;
        float post = (z == 0) ? 0.125f : 1.0f;
        float bv[4], sn[4], bn[4];
#pragma unroll
        for (int ni = 0; ni < 4; ni++)
            bv[ni] = bp[(cbase & 1023) + ni * 16 + l15];
        if (z < 2) {
            const float* ns = (z == 0) ? qn_s : kn_s;
            const float* nb = (z == 0) ? qn_b : kn_b;
#pragma unroll
            for (int ni = 0; ni < 4; ni++) {
                sn[ni] = ns[hd * 64 + ni * 16 + l15];
                bn[ni] = nb[hd * 64 + ni * 16 + l15];
            }
        }
#pragma unroll
        for (int mi = 0; mi < 4; mi++) {
            int rbase = row0 + wr + mi * 16 + quad * 4;
#pragma unroll
            for (int r = 0; r < 4; r++) {
                float v0 = acc[mi][0][r] + bv[0];
                float v1 = acc[mi][1][r] + bv[1];
                float v2 = acc[mi][2][r] + bv[2];
                float v3 = acc[mi][3][r] + bv[3];
                size_t rb = (size_t)(rbase + r) * N + cbase;
                if (z == 2) {
                    o0[rb + 0 * 16 + l15] = f2bf(v0);
                    o0[rb + 1 * 16 + l15] = f2bf(v1);
                    o0[rb + 2 * 16 + l15] = f2bf(v2);
                    o0[rb + 3 * 16 + l15] = f2bf(v3);
                } else {
                    float s  = v0 + v1 + v2 + v3;
                    float sq = v0 * v0 + v1 * v1 + v2 * v2 + v3 * v3;
#pragma unroll
                    for (int m = 1; m < 16; m <<= 1) {
                        s  += __shfl_xor(s,  m);
                        sq += __shfl_xor(sq, m);
                    }
                    float mean = s * (1.0f / 64.0f);
                    float var  = sq * (1.0f / 64.0f) - mean * mean;
                    float inv  = rsqrtf(var + 1e-6f);
                    o0[rb + 0 * 16 + l15] = f2bf(((v0 - mean) * inv * sn[0] + bn[0]) * post);
                    o0[rb + 1 * 16 + l15] = f2bf(((v1 - mean) * inv * sn[1] + bn[1]) * post);
                    o0[rb + 2 * 16 + l15] = f2bf(((v2 - mean) * inv * sn[2] + bn[2]) * post);
                    o0[rb + 3 * 16 + l15] = f2bf(((v3 - mean) * inv * sn[3] + bn[3]) * post);
                }
            }
        }
    }
}

// ---------------- fused GeGLU FFN GEMM, BK=64: H = (A@W1+b1)*gelu(A@W2+b2) --
__global__ __launch_bounds__(256, 2) void gemm_w12(const u16* __restrict__ A,
                                                   const u16* __restrict__ W12T,
                                                   const float* __restrict__ b1,
                                                   const float* __restrict__ b2,
                                                   u16* __restrict__ H) {
    __shared__ u16 As[128 * 64];
    __shared__ u16 B1s[128 * 64];
    __shared__ u16 B2s[128 * 64];
    int tid = threadIdx.x, wave = tid >> 6, lane = tid & 63;
    int quad = lane >> 4, l15 = lane & 15;
    int row0 = blockIdx.y * 128, col0 = blockIdx.x * 128;
    int wr = (wave >> 1) * 64, wc = (wave & 1) * 64;
    int swz = SW64(lane);

    f32x4 acc1[4][4] = {}, acc2[4][4] = {};

    const u16* gA  = A    + (size_t)(row0 + wave * 32 + (lane >> 3)) * 1024 + swz;
    const u16* gB1 = W12T + (size_t)(col0 + wave * 32 + (lane >> 3)) * 1024 + swz;
    const u16* gB2 = gB1  + (size_t)4096 * 1024;
    u16* lA  = &As [wave * 32 * 64];
    u16* lB1 = &B1s[wave * 32 * 64];
    u16* lB2 = &B2s[wave * 32 * 64];

    for (int k0 = 0; k0 < 1024; k0 += 64) {
        __syncthreads();
#pragma unroll
        for (int j = 0; j < 4; j++) {
            g2l16(gA  + k0 + j * 8 * 1024, lA  + j * 8 * 64);
            g2l16(gB1 + k0 + j * 8 * 1024, lB1 + j * 8 * 64);
            g2l16(gB2 + k0 + j * 8 * 1024, lB2 + j * 8 * 64);
        }
        __syncthreads();
#pragma unroll
        for (int kk = 0; kk < 2; kk++) {
            int rs = RS64(kk, quad, l15);
            bfrag af[4], b1f[4], b2f[4];
#pragma unroll
            for (int mi = 0; mi < 4; mi++)
                af[mi] = *(const bfrag*)&As[(wr + mi * 16 + l15) * 64 + rs];
#pragma unroll
            for (int ni = 0; ni < 4; ni++) {
                b1f[ni] = *(const bfrag*)&B1s[(wc + ni * 16 + l15) * 64 + rs];
                b2f[ni] = *(const bfrag*)&B2s[(wc + ni * 16 + l15) * 64 + rs];
            }
#pragma unroll
            for (int mi = 0; mi < 4; mi++)
#pragma unroll
                for (int ni = 0; ni < 4; ni++) {
                    acc1[mi][ni] = __builtin_amdgcn_mfma_f32_16x16x32_bf16(
                        af[mi], b1f[ni], acc1[mi][ni], 0, 0, 0);
                    acc2[mi][ni] = __builtin_amdgcn_mfma_f32_16x16x32_bf16(
                        af[mi], b2f[ni], acc2[mi][ni], 0, 0, 0);
                }
        }
    }

    float bv1[4], bv2[4];
    int cols[4];
#pragma unroll
    for (int ni = 0; ni < 4; ni++) {
        cols[ni] = col0 + wc + ni * 16 + l15;
        bv1[ni] = b1[cols[ni]];
        bv2[ni] = b2[cols[ni]];
    }
#pragma unroll
    for (int mi = 0; mi < 4; mi++) {
        int rbase = row0 + wr + mi * 16 + quad * 4;
#pragma unroll
        for (int r = 0; r < 4; r++) {
#pragma unroll
            for (int ni = 0; ni < 4; ni++) {
                float x1 = acc1[mi][ni][r] + bv1[ni];
                float x2 = acc2[mi][ni][r] + bv2[ni];
                H[(size_t)(rbase + r) * 4096 + cols[ni]] = f2bf(x1 * gelu_tanh(x2));
            }
        }
    }
}

// ---- fused Wo-reduce + residual + LN2: xmid = x+bo+p0+p1; xn2 = LN(xmid) ---
__global__ __launch_bounds__(256) void reduce_ln(const u16* __restrict__ p0,
                                                 const u16* __restrict__ p1,
                                                 const float* __restrict__ x,
                                                 const float* __restrict__ bo,
                                                 const float* __restrict__ s,
                                                 const float* __restrict__ b,
                                                 float* __restrict__ xmid,
                                                 u16* __restrict__ xn2) {
    int row = blockIdx.x, t = threadIdx.x;
    size_t i = (size_t)row * 1024 + t * 4;
    float4 xv = *(const float4*)&x[i];
    float4 bb = *(const float4*)&bo[t * 4];
    u16x4 a0 = *(const u16x4*)&p0[i];
    u16x4 a1 = *(const u16x4*)&p1[i];
    float4 v;
    v.x = xv.x + bb.x + bf2f(a0[0]) + bf2f(a1[0]);
    v.y = xv.y + bb.y + bf2f(a0[1]) + bf2f(a1[1]);
    v.z = xv.z + bb.z + bf2f(a0[2]) + bf2f(a1[2]);
    v.w = xv.w + bb.w + bf2f(a0[3]) + bf2f(a1[3]);
    *(float4*)&xmid[i] = v;
    float sum = v.x + v.y + v.z + v.w;
    float sq  = v.x * v.x + v.y * v.y + v.z * v.z + v.w * v.w;
#pragma unroll
    for (int off = 1; off < 64; off <<= 1) {
        sum += __shfl_xor(sum, off);
        sq  += __shfl_xor(sq,  off);
    }
    __shared__ float s1[4], s2[4];
    int wave = t >> 6;
    if ((t & 63) == 0) { s1[wave] = sum; s2[wave] = sq; }
    __syncthreads();
    sum = s1[0] + s1[1] + s1[2] + s1[3];
    sq  = s2[0] + s2[1] + s2[2] + s2[3];
    float mean = sum * (1.0f / 1024.0f);
    float var  = sq  * (1.0f / 1024.0f) - mean * mean;
    float inv  = rsqrtf(var + 1e-6f);
    float4 sc = ((const float4*)s)[t], lb = ((const float4*)b)[t];
    u16x4 o;
    o[0] = f2bf((v.x - mean) * inv * sc.x + lb.x);
    o[1] = f2bf((v.y - mean) * inv * sc.y + lb.y);
    o[2] = f2bf((v.z - mean) * inv * sc.z + lb.z);
    o[3] = f2bf((v.w - mean) * inv * sc.w + lb.w);
    *(u16x4*)&xn2[i] = o;
}

// ---------------- reduce: out = xmid + b3 + sum of 4 bf16 partials ----------
__global__ __launch_bounds__(256) void reduce4(const u16* __restrict__ p0,
                                               const u16* __restrict__ p1,
                                               const u16* __restrict__ p2,
                                               const u16* __restrict__ p3,
                                               const float* __restrict__ xmid,
                                               const float* __restrict__ b3,
                                               float* __restrict__ out) {
    size_t i = ((size_t)blockIdx.x * 256 + threadIdx.x) * 4;
    float4 xm = *(const float4*)&xmid[i];
    float4 bb = *(const float4*)&b3[i & 1023];
    u16x4 a0 = *(const u16x4*)&p0[i];
    u16x4 a1 = *(const u16x4*)&p1[i];
    u16x4 a2 = *(const u16x4*)&p2[i];
    u16x4 a3 = *(const u16x4*)&p3[i];
    float4 o;
    o.x = xm.x + bb.x + bf2f(a0[0]) + bf2f(a1[0]) + bf2f(a2[0]) + bf2f(a3[0]);
    o.y = xm.y + bb.y + bf2f(a0[1]) + bf2f(a1[1]) + bf2f(a2[1]) + bf2f(a3[1]);
    o.z = xm.z + bb.z + bf2f(a0[2]) + bf2f(a1[2]) + bf2f(a2[2]) + bf2f(a3[2]);
    o.w = xm.w + bb.w + bf2f(a0[3]) + bf2f(a1[3]) + bf2f(a2[3]) + bf2f(a3[3]);
    *(float4*)&out[i] = o;
}

// ---------------- Flash attention on packed qkv [4096][3072] ----------------
#define LP 72
__global__ __launch_bounds__(256) void flash(const u16* __restrict__ qkv,
                                             u16* __restrict__ o) {
    int qt = blockIdx.x, h = blockIdx.y, b = blockIdx.z;
    int tid = threadIdx.x, wave = tid >> 6, lane = tid & 63;
    int quad = lane >> 4, l15 = lane & 15;

    __shared__ u16 Qs[128 * LP];
    __shared__ u16 Ks[64 * LP];
    __shared__ u16 Vt[64 * LP];   // [d][key]
    __shared__ u16 Ps[128 * LP];

    {
        int row = tid >> 1, half = tid & 1;
        const u16* src = qkv + (size_t)(b * 1024 + qt * 128 + row) * 3072 + h * 64 + half * 32;
        u16* dst = &Qs[row * LP + half * 32];
#pragma unroll
        for (int i = 0; i < 4; i++)
            ((u16x8*)dst)[i] = ((const u16x8*)src)[i];
    }

    f32x4 accO[2][4] = {};
    float m_run[2][4], l_run[2][4];
#pragma unroll
    for (int rt = 0; rt < 2; rt++)
#pragma unroll
        for (int r = 0; r < 4; r++) { m_run[rt][r] = -1e30f; l_run[rt][r] = 0.0f; }

    for (int kt = 0; kt < 16; kt++) {
        __syncthreads();
        {
            int row = tid >> 2, seg = tid & 3;
            size_t gb = (size_t)(b * 1024 + kt * 64 + row) * 3072 + h * 64;
            const u16* ksrc = qkv + gb + 1024 + seg * 16;
            *(u16x8*)&Ks[row * LP + seg * 16]     = *(const u16x8*)ksrc;
            *(u16x8*)&Ks[row * LP + seg * 16 + 8] = *(const u16x8*)(ksrc + 8);
            const u16* vsrc = qkv + gb + 2048 + seg * 16;
            u16x8 v0 = *(const u16x8*)vsrc, v1 = *(const u16x8*)(vsrc + 8);
#pragma unroll
            for (int j = 0; j < 8; j++) Vt[(seg * 16 + j) * LP + row]     = v0[j];
#pragma unroll
            for (int j = 0; j < 8; j++) Vt[(seg * 16 + 8 + j) * LP + row] = v1[j];
        }
        __syncthreads();

        f32x4 accS[2][4] = {};
#pragma unroll
        for (int kk = 0; kk < 2; kk++) {
            bfrag aq[2];
#pragma unroll
            for (int rt = 0; rt < 2; rt++)
                aq[rt] = *(const bfrag*)&Qs[(wave * 32 + rt * 16 + l15) * LP + kk * 32 + quad * 8];
#pragma unroll
            for (int ct = 0; ct < 4; ct++) {
                bfrag bk = *(const bfrag*)&Ks[(ct * 16 + l15) * LP + kk * 32 + quad * 8];
                accS[0][ct] = __builtin_amdgcn_mfma_f32_16x16x32_bf16(aq[0], bk, accS[0][ct], 0, 0, 0);
                accS[1][ct] = __builtin_amdgcn_mfma_f32_16x16x32_bf16(aq[1], bk, accS[1][ct], 0, 0, 0);
            }
        }

#pragma unroll
        for (int rt = 0; rt < 2; rt++) {
#pragma unroll
            for (int r = 0; r < 4; r++) {
                float tmax = accS[rt][0][r];
#pragma unroll
                for (int ct = 1; ct < 4; ct++) tmax = fmaxf(tmax, accS[rt][ct][r]);
#pragma unroll
                for (int m = 1; m < 16; m <<= 1) tmax = fmaxf(tmax, __shfl_xor(tmax, m));
                float mnew  = fmaxf(m_run[rt][r], tmax);
                float alpha = __expf(m_run[rt][r] - mnew);
                float lsum = 0.0f;
                float p[4];
#pragma unroll
                for (int ct = 0; ct < 4; ct++) {
                    p[ct] = __expf(accS[rt][ct][r] - mnew);
                    lsum += p[ct];
                }
#pragma unroll
                for (int m = 1; m < 16; m <<= 1) lsum += __shfl_xor(lsum, m);
                l_run[rt][r] = l_run[rt][r] * alpha + lsum;
                m_run[rt][r] = mnew;
#pragma unroll
                for (int oc = 0; oc < 4; oc++) accO[rt][oc][r] *= alpha;
                int prow = wave * 32 + rt * 16 + quad * 4 + r;
#pragma unroll
                for (int ct = 0; ct < 4; ct++)
                    Ps[prow * LP + ct * 16 + l15] = f2bf(p[ct]);
            }
        }

#pragma unroll
        for (int kk = 0; kk < 2; kk++) {
            bfrag ap[2];
#pragma unroll
            for (int rt = 0; rt < 2; rt++)
                ap[rt] = *(const bfrag*)&Ps[(wave * 32 + rt * 16 + l15) * LP + kk * 32 + quad * 8];
#pragma unroll
            for (int oc = 0; oc < 4; oc++) {
                bfrag bv = *(const bfrag*)&Vt[(oc * 16 + l15) * LP + kk * 32 + quad * 8];
                accO[0][oc] = __builtin_amdgcn_mfma_f32_16x16x32_bf16(ap[0], bv, accO[0][oc], 0, 0, 0);
                accO[1][oc] = __builtin_amdgcn_mfma_f32_16x16x32_bf16(ap[1], bv, accO[1][oc], 0, 0, 0);
            }
        }
    }

#pragma unroll
    for (int rt = 0; rt < 2; rt++) {
#pragma unroll
        for (int r = 0; r < 4; r++) {
            int srow = qt * 128 + wave * 32 + rt * 16 + quad * 4 + r;
            float linv = 1.0f / l_run[rt][r];
#pragma unroll
            for (int oc = 0; oc < 4; oc++)
                o[(size_t)(b * 1024 + srow) * 1024 + h * 64 + oc * 16 + l15] =
                    f2bf(accO[rt][oc][r] * linv);
        }
    }
}

// ---------------------------------------------------------------------------
extern "C" void kernel_launch(void* const* d_in, const int* in_sizes, int n_in,
                              void* d_out, int out_size, void* d_ws, size_t ws_size,
                              hipStream_t stream) {
    const float* x     = (const float*)d_in[0];
    const float* ln1_s = (const float*)d_in[2];
    const float* ln1_b = (const float*)d_in[3];
    const float* Wq = (const float*)d_in[4];  const float* bq = (const float*)d_in[5];
    const float* Wk = (const float*)d_in[6];  const float* bk = (const float*)d_in[7];
    const float* Wv = (const float*)d_in[8];  const float* bv = (const float*)d_in[9];
    const float* qn_s = (const float*)d_in[10]; const float* qn_b = (const float*)d_in[11];
    const float* kn_s = (const float*)d_in[12]; const float* kn_b = (const float*)d_in[13];
    const float* Wo = (const float*)d_in[14]; const float* bo = (const float*)d_in[15];
    const float* ln2_s = (const float*)d_in[16]; const float* ln2_b = (const float*)d_in[17];
    const float* W1 = (const float*)d_in[18]; const float* b1 = (const float*)d_in[19];
    const float* W2 = (const float*)d_in[20]; const float* b2 = (const float*)d_in[21];
    const float* W3 = (const float*)d_in[22]; const float* b3 = (const float*)d_in[23];
    float* out = (float*)d_out;

    char* ws = (char*)d_ws;
    const size_t MB = (size_t)1 << 20;
    u16* WqkvT = (u16*)(ws + 0);         // 0..6    dead after QKV; then p0 @0
    u16* WoT   = (u16*)(ws + 6 * MB);    // 6..8    dead after Wo
    u16* W12T  = (u16*)(ws + 8 * MB);    // 8..24   dead after W12; then p1/p2
    u16* W3T   = (u16*)(ws + 24 * MB);   // 24..32  dead after splitk
    u16* xn1   = (u16*)(ws + 32 * MB);   // 32..40  dead after QKV
    u16* attn  = (u16*)(ws + 32 * MB);   //   reuse: dead after Wo-gemm
    u16* xn2   = (u16*)(ws + 32 * MB);   //   reuse: dead after W12
    u16* qkv   = (u16*)(ws + 40 * MB);   // 40..64  dead after flash
    float* xmid = (float*)(ws + 40 * MB);//   reuse: 40..56, alive until reduce4
    u16* p3    = (u16*)(ws + 56 * MB);   // 56..64
    u16* h     = (u16*)(ws + 64 * MB);   // 64..96  dead after splitk
    u16* wp0   = (u16*)(ws + 64 * MB);   // Wo partials: 64..72, 72..80
    u16* wp1   = (u16*)(ws + 72 * MB);   //   dead after reduce_ln (before h)
    u16* p0    = (u16*)(ws + 0);
    u16* p1    = (u16*)(ws + 8 * MB);
    u16* p2    = (u16*)(ws + 16 * MB);
    // peak = 96 MB

    // weight transposes + ln1 fused
    wtln<<<20480, 256, 0, stream>>>(Wq, Wk, Wv, Wo, W1, W2, W3,
                                    WqkvT, WoT, W12T, W3T,
                                    x, ln1_s, ln1_b, xn1);

    // fused QKV + per-head QK-norm (BK=64)
    gemm64<4><<<dim3(24, 32, 1), 256, 0, stream>>>(
        xn1, WqkvT, bq, bk, bv, qn_s, qn_b, kn_s, kn_b,
        qkv, nullptr, nullptr, nullptr, 4096, 3072, 1024, 1024);

    flash<<<dim3(8, 16, 4), 256, 0, stream>>>(qkv, attn);

    // Wo split-K=2 partials (BK=64)
    gemm64<0><<<dim3(8, 32, 2), 256, 0, stream>>>(
        attn, WoT, nullptr, nullptr, nullptr, nullptr, nullptr, nullptr, nullptr,
        wp0, wp1, nullptr, nullptr, 4096, 1024, 1024, 512);

    // xmid = x + bo + wp0 + wp1; xn2 = LN2(xmid)
    reduce_ln<<<4096, 256, 0, stream>>>(wp0, wp1, x, bo, ln2_s, ln2_b, xmid, xn2);

    // fused GeGLU FFN (BK=64): h = (xn2@W1+b1) * gelu(xn2@W2+b2)
    gemm_w12<<<dim3(32, 32), 256, 0, stream>>>(xn2, W12T, b1, b2, h);

    // W3 split-K=4 partials (BK=64)
    gemm64<0><<<dim3(8, 32, 4), 256, 0, stream>>>(
        h, W3T, nullptr, nullptr, nullptr, nullptr, nullptr, nullptr, nullptr,
        p0, p1, p2, p3, 4096, 1024, 4096, 1024);

    // out = xmid + b3 + sum(partials)
    reduce4<<<4096, 256, 0, stream>>>(p0, p1, p2, p3, xmid, b3, out);
}

// Round 7
// 411.671 us; speedup vs baseline: 1.2517x; 1.0574x over previous
//
#include <hip/hip_runtime.h>

typedef unsigned short u16;
typedef __bf16  bfrag  __attribute__((ext_vector_type(8)));   // MFMA A/B operand (4 VGPRs)
typedef float   f32x4  __attribute__((ext_vector_type(4)));   // MFMA C/D operand
typedef u16     u16x8  __attribute__((ext_vector_type(8)));
typedef u16     u16x4  __attribute__((ext_vector_type(4)));

__device__ __forceinline__ float bf2f(u16 u) {
    unsigned v = ((unsigned)u) << 16;
    return __builtin_bit_cast(float, v);
}
__device__ __forceinline__ u16 f2bf(float f) {   // round-to-nearest-even
    unsigned x = __builtin_bit_cast(unsigned, f);
    unsigned r = (x + 0x7fffu + ((x >> 16) & 1u)) >> 16;
    return (u16)r;
}
__device__ __forceinline__ void g2l16(const u16* g, u16* l) {
    // 16B per lane -> lds_base + lane*16 (wave-uniform LDS base)
    __builtin_amdgcn_global_load_lds((__attribute__((address_space(1))) void*)g,
                                     (__attribute__((address_space(3))) void*)l, 16, 0, 0);
}
__device__ __forceinline__ float gelu_tanh(float x) {
    // 0.5x(1+tanh(c)) == x * sigmoid(2c)
    float c = 1.5957691216057308f * (x + 0.044715f * x * x * x);
    return x * __frcp_rn(1.0f + __expf(-c));
}

// BK=64 LDS tiles: row = 128 B = 8 chunks of 16 B = exactly one 32-bank stripe.
// Swizzle phys_chunk = logical_chunk ^ (row & 7): conflict-free frag reads.
#define SW64(l)   (((((l) & 7) ^ (((l) >> 3) & 7))) * 8)
#define RS64(kk, quad, l15)  (((((kk) * 4 + (quad)) ^ ((l15) & 7))) * 8)

// ---------------- weight transposes + LN1 fused in ONE kernel ---------------
__global__ __launch_bounds__(256) void wtln(
        const float* __restrict__ Wq, const float* __restrict__ Wk,
        const float* __restrict__ Wv, const float* __restrict__ Wo,
        const float* __restrict__ W1, const float* __restrict__ W2,
        const float* __restrict__ W3,
        u16* __restrict__ WqkvT, u16* __restrict__ WoT,
        u16* __restrict__ W12T, u16* __restrict__ W3T,
        const float* __restrict__ x, const float* __restrict__ ln1_s,
        const float* __restrict__ ln1_b, u16* __restrict__ xn1) {
    __shared__ float tile[32][33];
    int blk = blockIdx.x;
    if (blk >= 16384) {
        int row = blk - 16384, t = threadIdx.x;
        float4 v = ((const float4*)(x + (size_t)row * 1024))[t];
        float sum = v.x + v.y + v.z + v.w;
        float sq  = v.x * v.x + v.y * v.y + v.z * v.z + v.w * v.w;
#pragma unroll
        for (int off = 1; off < 64; off <<= 1) {
            sum += __shfl_xor(sum, off);
            sq  += __shfl_xor(sq,  off);
        }
        float* s1 = &tile[0][0];
        float* s2 = &tile[0][8];
        int wave = t >> 6;
        if ((t & 63) == 0) { s1[wave] = sum; s2[wave] = sq; }
        __syncthreads();
        sum = s1[0] + s1[1] + s1[2] + s1[3];
        sq  = s2[0] + s2[1] + s2[2] + s2[3];
        float mean = sum * (1.0f / 1024.0f);
        float var  = sq  * (1.0f / 1024.0f) - mean * mean;
        float inv  = rsqrtf(var + 1e-6f);
        float4 sc = ((const float4*)ln1_s)[t], bb = ((const float4*)ln1_b)[t];
        u16x4 o;
        o[0] = f2bf((v.x - mean) * inv * sc.x + bb.x);
        o[1] = f2bf((v.y - mean) * inv * sc.y + bb.y);
        o[2] = f2bf((v.z - mean) * inv * sc.z + bb.z);
        o[3] = f2bf((v.w - mean) * inv * sc.w + bb.w);
        *(u16x4*)&xn1[(size_t)row * 1024 + t * 4] = o;
        return;
    }
    const float* W; u16* Wt; int R, C, local;
    if (blk < 3072) {
        int w = blk >> 10; local = blk & 1023;
        W = (w == 0) ? Wq : (w == 1) ? Wk : Wv;
        Wt = WqkvT + (size_t)w * 1024 * 1024; R = 1024; C = 1024;
    } else if (blk < 4096) { W = Wo; Wt = WoT; R = 1024; C = 1024; local = blk - 3072; }
    else if (blk < 8192)   { W = W1; Wt = W12T; R = 1024; C = 4096; local = blk - 4096; }
    else if (blk < 12288)  { W = W2; Wt = W12T + (size_t)4096 * 1024; R = 1024; C = 4096; local = blk - 8192; }
    else                   { W = W3; Wt = W3T; R = 4096; C = 1024; local = blk - 12288; }
    int tiles_x = C >> 5;
    int c0 = (local % tiles_x) * 32, r0 = (local / tiles_x) * 32;
    int tx = threadIdx.x & 31, ty = threadIdx.x >> 5;
#pragma unroll
    for (int i = 0; i < 32; i += 8)
        tile[ty + i][tx] = W[(size_t)(r0 + ty + i) * C + c0 + tx];
    __syncthreads();
#pragma unroll
    for (int i = 0; i < 32; i += 8)
        Wt[(size_t)(c0 + ty + i) * R + r0 + tx] = f2bf(tile[tx][ty + i]);
}

// ---- gemm64: 4-wave 128x128 block tile, 64x64 wave tile, BK=64 -------------
// EPI 0: bf16 partial store to o[kz] (split-K) | 4: QKV + per-head LN.
template <int EPI>
__global__ __launch_bounds__(256, 3) void gemm64(const u16* __restrict__ A,
                                                 const u16* __restrict__ Bt,
                                                 const float* __restrict__ bias,
                                                 const float* __restrict__ bias2,
                                                 const float* __restrict__ bias3,
                                                 const float* __restrict__ qn_s,
                                                 const float* __restrict__ qn_b,
                                                 const float* __restrict__ kn_s,
                                                 const float* __restrict__ kn_b,
                                                 u16* __restrict__ o0,
                                                 u16* __restrict__ o1,
                                                 u16* __restrict__ o2,
                                                 u16* __restrict__ o3,
                                                 int M, int N, int K, int Klen) {
    __shared__ u16 As[128 * 64];
    __shared__ u16 Bs[128 * 64];
    int tid = threadIdx.x, wave = tid >> 6, lane = tid & 63;
    int quad = lane >> 4, l15 = lane & 15;
    int row0 = blockIdx.y * 128, col0 = blockIdx.x * 128;
    int kz = blockIdx.z;
    int wr = (wave >> 1) * 64, wc = (wave & 1) * 64;
    int swz = SW64(lane);

    f32x4 acc[4][4] = {};

    const u16* gA = A  + (size_t)(row0 + wave * 32 + (lane >> 3)) * K + kz * Klen + swz;
    const u16* gB = Bt + (size_t)(col0 + wave * 32 + (lane >> 3)) * K + kz * Klen + swz;
    u16* lA = &As[wave * 32 * 64];
    u16* lB = &Bs[wave * 32 * 64];

    for (int k0 = 0; k0 < Klen; k0 += 64) {
        __syncthreads();
#pragma unroll
        for (int j = 0; j < 4; j++) {
            g2l16(gA + k0 + j * 8 * K, lA + j * 8 * 64);
            g2l16(gB + k0 + j * 8 * K, lB + j * 8 * 64);
        }
        __syncthreads();
#pragma unroll
        for (int kk = 0; kk < 2; kk++) {
            int rs = RS64(kk, quad, l15);
            bfrag af[4], bf[4];
#pragma unroll
            for (int mi = 0; mi < 4; mi++)
                af[mi] = *(const bfrag*)&As[(wr + mi * 16 + l15) * 64 + rs];
#pragma unroll
            for (int ni = 0; ni < 4; ni++)
                bf[ni] = *(const bfrag*)&Bs[(wc + ni * 16 + l15) * 64 + rs];
#pragma unroll
            for (int mi = 0; mi < 4; mi++)
#pragma unroll
                for (int ni = 0; ni < 4; ni++)
                    acc[mi][ni] = __builtin_amdgcn_mfma_f32_16x16x32_bf16(
                        af[mi], bf[ni], acc[mi][ni], 0, 0, 0);
        }
    }

    if (EPI == 0) {
        u16* P = (kz == 0) ? o0 : (kz == 1) ? o1 : (kz == 2) ? o2 : o3;
#pragma unroll
        for (int mi = 0; mi < 4; mi++) {
            int rbase = row0 + wr + mi * 16 + quad * 4;
#pragma unroll
            for (int r = 0; r < 4; r++)
#pragma unroll
                for (int ni = 0; ni < 4; ni++)
                    P[(size_t)(rbase + r) * N + col0 + wc + ni * 16 + l15] =
                        f2bf(acc[mi][ni][r]);
        }
    } else {
        int cbase = col0 + wc;
        int z = cbase >> 10;              // 0=q, 1=k, 2=v
        int hd = (cbase >> 6) & 15;
        const float* bp = (z == 0) ? bias : (z == 1) ? bias2 : bias3;
        float post = (z == 0) ? 0.125f : 1.0f;
        float bv[4], sn[4], bn[4];
#pragma unroll
        for (int ni = 0; ni < 4; ni++)
            bv[ni] = bp[(cbase & 1023) + ni * 16 + l15];
        if (z < 2) {
            const float* ns = (z == 0) ? qn_s : kn_s;
            const float* nb = (z == 0) ? qn_b : kn_b;
#pragma unroll
            for (int ni = 0; ni < 4; ni++) {
                sn[ni] = ns[hd * 64 + ni * 16 + l15];
                bn[ni] = nb[hd * 64 + ni * 16 + l15];
            }
        }
#pragma unroll
        for (int mi = 0; mi < 4; mi++) {
            int rbase = row0 + wr + mi * 16 + quad * 4;
#pragma unroll
            for (int r = 0; r < 4; r++) {
                float v0 = acc[mi][0][r] + bv[0];
                float v1 = acc[mi][1][r] + bv[1];
                float v2 = acc[mi][2][r] + bv[2];
                float v3 = acc[mi][3][r] + bv[3];
                size_t rb = (size_t)(rbase + r) * N + cbase;
                if (z == 2) {
                    o0[rb + 0 * 16 + l15] = f2bf(v0);
                    o0[rb + 1 * 16 + l15] = f2bf(v1);
                    o0[rb + 2 * 16 + l15] = f2bf(v2);
                    o0[rb + 3 * 16 + l15] = f2bf(v3);
                } else {
                    float s  = v0 + v1 + v2 + v3;
                    float sq = v0 * v0 + v1 * v1 + v2 * v2 + v3 * v3;
#pragma unroll
                    for (int m = 1; m < 16; m <<= 1) {
                        s  += __shfl_xor(s,  m);
                        sq += __shfl_xor(sq, m);
                    }
                    float mean = s * (1.0f / 64.0f);
                    float var  = sq * (1.0f / 64.0f) - mean * mean;
                    float inv  = rsqrtf(var + 1e-6f);
                    o0[rb + 0 * 16 + l15] = f2bf(((v0 - mean) * inv * sn[0] + bn[0]) * post);
                    o0[rb + 1 * 16 + l15] = f2bf(((v1 - mean) * inv * sn[1] + bn[1]) * post);
                    o0[rb + 2 * 16 + l15] = f2bf(((v2 - mean) * inv * sn[2] + bn[2]) * post);
                    o0[rb + 3 * 16 + l15] = f2bf(((v3 - mean) * inv * sn[3] + bn[3]) * post);
                }
            }
        }
    }
}

// ---------------- fused GeGLU FFN GEMM, BK=64 -------------------------------
__global__ __launch_bounds__(256, 2) void gemm_w12(const u16* __restrict__ A,
                                                   const u16* __restrict__ W12T,
                                                   const float* __restrict__ b1,
                                                   const float* __restrict__ b2,
                                                   u16* __restrict__ H) {
    __shared__ u16 As[128 * 64];
    __shared__ u16 B1s[128 * 64];
    __shared__ u16 B2s[128 * 64];
    int tid = threadIdx.x, wave = tid >> 6, lane = tid & 63;
    int quad = lane >> 4, l15 = lane & 15;
    int row0 = blockIdx.y * 128, col0 = blockIdx.x * 128;
    int wr = (wave >> 1) * 64, wc = (wave & 1) * 64;
    int swz = SW64(lane);

    f32x4 acc1[4][4] = {}, acc2[4][4] = {};

    const u16* gA  = A    + (size_t)(row0 + wave * 32 + (lane >> 3)) * 1024 + swz;
    const u16* gB1 = W12T + (size_t)(col0 + wave * 32 + (lane >> 3)) * 1024 + swz;
    const u16* gB2 = gB1  + (size_t)4096 * 1024;
    u16* lA  = &As [wave * 32 * 64];
    u16* lB1 = &B1s[wave * 32 * 64];
    u16* lB2 = &B2s[wave * 32 * 64];

    for (int k0 = 0; k0 < 1024; k0 += 64) {
        __syncthreads();
#pragma unroll
        for (int j = 0; j < 4; j++) {
            g2l16(gA  + k0 + j * 8 * 1024, lA  + j * 8 * 64);
            g2l16(gB1 + k0 + j * 8 * 1024, lB1 + j * 8 * 64);
            g2l16(gB2 + k0 + j * 8 * 1024, lB2 + j * 8 * 64);
        }
        __syncthreads();
#pragma unroll
        for (int kk = 0; kk < 2; kk++) {
            int rs = RS64(kk, quad, l15);
            bfrag af[4], b1f[4], b2f[4];
#pragma unroll
            for (int mi = 0; mi < 4; mi++)
                af[mi] = *(const bfrag*)&As[(wr + mi * 16 + l15) * 64 + rs];
#pragma unroll
            for (int ni = 0; ni < 4; ni++) {
                b1f[ni] = *(const bfrag*)&B1s[(wc + ni * 16 + l15) * 64 + rs];
                b2f[ni] = *(const bfrag*)&B2s[(wc + ni * 16 + l15) * 64 + rs];
            }
#pragma unroll
            for (int mi = 0; mi < 4; mi++)
#pragma unroll
                for (int ni = 0; ni < 4; ni++) {
                    acc1[mi][ni] = __builtin_amdgcn_mfma_f32_16x16x32_bf16(
                        af[mi], b1f[ni], acc1[mi][ni], 0, 0, 0);
                    acc2[mi][ni] = __builtin_amdgcn_mfma_f32_16x16x32_bf16(
                        af[mi], b2f[ni], acc2[mi][ni], 0, 0, 0);
                }
        }
    }

    float bv1[4], bv2[4];
    int cols[4];
#pragma unroll
    for (int ni = 0; ni < 4; ni++) {
        cols[ni] = col0 + wc + ni * 16 + l15;
        bv1[ni] = b1[cols[ni]];
        bv2[ni] = b2[cols[ni]];
    }
#pragma unroll
    for (int mi = 0; mi < 4; mi++) {
        int rbase = row0 + wr + mi * 16 + quad * 4;
#pragma unroll
        for (int r = 0; r < 4; r++) {
#pragma unroll
            for (int ni = 0; ni < 4; ni++) {
                float x1 = acc1[mi][ni][r] + bv1[ni];
                float x2 = acc2[mi][ni][r] + bv2[ni];
                H[(size_t)(rbase + r) * 4096 + cols[ni]] = f2bf(x1 * gelu_tanh(x2));
            }
        }
    }
}

// ---- fused Wo-reduce + residual + LN2 --------------------------------------
__global__ __launch_bounds__(256) void reduce_ln(const u16* __restrict__ p0,
                                                 const u16* __restrict__ p1,
                                                 const float* __restrict__ x,
                                                 const float* __restrict__ bo,
                                                 const float* __restrict__ s,
                                                 const float* __restrict__ b,
                                                 float* __restrict__ xmid,
                                                 u16* __restrict__ xn2) {
    int row = blockIdx.x, t = threadIdx.x;
    size_t i = (size_t)row * 1024 + t * 4;
    float4 xv = *(const float4*)&x[i];
    float4 bb = *(const float4*)&bo[t * 4];
    u16x4 a0 = *(const u16x4*)&p0[i];
    u16x4 a1 = *(const u16x4*)&p1[i];
    float4 v;
    v.x = xv.x + bb.x + bf2f(a0[0]) + bf2f(a1[0]);
    v.y = xv.y + bb.y + bf2f(a0[1]) + bf2f(a1[1]);
    v.z = xv.z + bb.z + bf2f(a0[2]) + bf2f(a1[2]);
    v.w = xv.w + bb.w + bf2f(a0[3]) + bf2f(a1[3]);
    *(float4*)&xmid[i] = v;
    float sum = v.x + v.y + v.z + v.w;
    float sq  = v.x * v.x + v.y * v.y + v.z * v.z + v.w * v.w;
#pragma unroll
    for (int off = 1; off < 64; off <<= 1) {
        sum += __shfl_xor(sum, off);
        sq  += __shfl_xor(sq,  off);
    }
    __shared__ float s1[4], s2[4];
    int wave = t >> 6;
    if ((t & 63) == 0) { s1[wave] = sum; s2[wave] = sq; }
    __syncthreads();
    sum = s1[0] + s1[1] + s1[2] + s1[3];
    sq  = s2[0] + s2[1] + s2[2] + s2[3];
    float mean = sum * (1.0f / 1024.0f);
    float var  = sq  * (1.0f / 1024.0f) - mean * mean;
    float inv  = rsqrtf(var + 1e-6f);
    float4 sc = ((const float4*)s)[t], lb = ((const float4*)b)[t];
    u16x4 o;
    o[0] = f2bf((v.x - mean) * inv * sc.x + lb.x);
    o[1] = f2bf((v.y - mean) * inv * sc.y + lb.y);
    o[2] = f2bf((v.z - mean) * inv * sc.z + lb.z);
    o[3] = f2bf((v.w - mean) * inv * sc.w + lb.w);
    *(u16x4*)&xn2[i] = o;
}

// ---------------- reduce: out = xmid + b3 + sum of 4 bf16 partials ----------
__global__ __launch_bounds__(256) void reduce4(const u16* __restrict__ p0,
                                               const u16* __restrict__ p1,
                                               const u16* __restrict__ p2,
                                               const u16* __restrict__ p3,
                                               const float* __restrict__ xmid,
                                               const float* __restrict__ b3,
                                               float* __restrict__ out) {
    size_t i = ((size_t)blockIdx.x * 256 + threadIdx.x) * 4;
    float4 xm = *(const float4*)&xmid[i];
    float4 bb = *(const float4*)&b3[i & 1023];
    u16x4 a0 = *(const u16x4*)&p0[i];
    u16x4 a1 = *(const u16x4*)&p1[i];
    u16x4 a2 = *(const u16x4*)&p2[i];
    u16x4 a3 = *(const u16x4*)&p3[i];
    float4 o;
    o.x = xm.x + bb.x + bf2f(a0[0]) + bf2f(a1[0]) + bf2f(a2[0]) + bf2f(a3[0]);
    o.y = xm.y + bb.y + bf2f(a0[1]) + bf2f(a1[1]) + bf2f(a2[1]) + bf2f(a3[1]);
    o.z = xm.z + bb.z + bf2f(a0[2]) + bf2f(a1[2]) + bf2f(a2[2]) + bf2f(a3[2]);
    o.w = xm.w + bb.w + bf2f(a0[3]) + bf2f(a1[3]) + bf2f(a2[3]) + bf2f(a3[3]);
    *(float4*)&out[i] = o;
}

// ---------------- Flash attention v2 ----------------------------------------
// grid (16 qt, 16 h, 4 b); 256 threads; 64-row Q tiles (16 rows/wave).
// Q frags direct from global; no-max softmax (|s|<=8 guaranteed by QK-norm:
// ||q*0.125||=1, ||k||=8 -> exp(s) <= e^8, fp32-safe); lane-local l partials
// reduced once in the epilogue. Vt staged seg=wave/key=lane (conflict-free
// ds_write_b16); Ps stride 68 u16 (quad bank-groups disjoint; b64-aligned).
#define LPK 72
#define LPV 72
#define LPP 68
__global__ __launch_bounds__(256, 4) void flash(const u16* __restrict__ qkv,
                                                u16* __restrict__ o) {
    int qt = blockIdx.x, h = blockIdx.y, b = blockIdx.z;
    int tid = threadIdx.x, wave = tid >> 6, lane = tid & 63;
    int quad = lane >> 4, l15 = lane & 15;

    __shared__ u16 Ks[64 * LPK];
    __shared__ u16 Vt[64 * LPV];   // [d][key]
    __shared__ u16 Ps[64 * LPP];

    // Q A-fragments straight from global (rows wave*16+l15, 16B contiguous)
    const u16* qrow = qkv + (size_t)(b * 1024 + qt * 64 + wave * 16 + l15) * 3072
                      + h * 64 + quad * 8;
    bfrag aq0 = *(const bfrag*)qrow;
    bfrag aq1 = *(const bfrag*)(qrow + 32);

    f32x4 accO[4] = {};
    float l_run[4] = {0.f, 0.f, 0.f, 0.f};

    for (int kt = 0; kt < 16; kt++) {
        __syncthreads();
        {   // K rows: row = tid>>2, seg = tid&3 (vector writes)
            int row = tid >> 2, seg = tid & 3;
            const u16* ksrc = qkv + (size_t)(b * 1024 + kt * 64 + row) * 3072
                              + 1024 + h * 64 + seg * 16;
            *(u16x8*)&Ks[row * LPK + seg * 16]     = *(const u16x8*)ksrc;
            *(u16x8*)&Ks[row * LPK + seg * 16 + 8] = *(const u16x8*)(ksrc + 8);
        }
        {   // V transposed: seg = wave, key = lane -> 64 consecutive u16/write
            const u16* vsrc = qkv + (size_t)(b * 1024 + kt * 64 + lane) * 3072
                              + 2048 + h * 64 + wave * 16;
            u16x8 v0 = *(const u16x8*)vsrc, v1 = *(const u16x8*)(vsrc + 8);
#pragma unroll
            for (int j = 0; j < 8; j++) Vt[(wave * 16 + j) * LPV + lane]     = v0[j];
#pragma unroll
            for (int j = 0; j < 8; j++) Vt[(wave * 16 + 8 + j) * LPV + lane] = v1[j];
        }
        __syncthreads();

        // S = Q x K^T over 64 keys
        f32x4 accS[4] = {};
#pragma unroll
        for (int ct = 0; ct < 4; ct++) {
            bfrag bk0 = *(const bfrag*)&Ks[(ct * 16 + l15) * LPK + quad * 8];
            bfrag bk1 = *(const bfrag*)&Ks[(ct * 16 + l15) * LPK + 32 + quad * 8];
            accS[ct] = __builtin_amdgcn_mfma_f32_16x16x32_bf16(aq0, bk0, accS[ct], 0, 0, 0);
            accS[ct] = __builtin_amdgcn_mfma_f32_16x16x32_bf16(aq1, bk1, accS[ct], 0, 0, 0);
        }

        // p = exp(s) (no max needed), lane-local l partial, write P
#pragma unroll
        for (int r = 0; r < 4; r++) {
            float p0 = __expf(accS[0][r]);
            float p1 = __expf(accS[1][r]);
            float p2 = __expf(accS[2][r]);
            float p3 = __expf(accS[3][r]);
            l_run[r] += (p0 + p1) + (p2 + p3);
            int pbase = (wave * 16 + quad * 4 + r) * LPP + l15;
            Ps[pbase + 0]  = f2bf(p0);
            Ps[pbase + 16] = f2bf(p1);
            Ps[pbase + 32] = f2bf(p2);
            Ps[pbase + 48] = f2bf(p3);
        }

        // O += P x V  (ap via two b64 reads; Vt rows give b128 B-frags)
#pragma unroll
        for (int kk = 0; kk < 2; kk++) {
            const u16* pp = &Ps[(wave * 16 + l15) * LPP + kk * 32 + quad * 8];
            u16x4 lo = *(const u16x4*)pp;
            u16x4 hi = *(const u16x4*)(pp + 4);
            u16x8 apu;
            apu[0] = lo[0]; apu[1] = lo[1]; apu[2] = lo[2]; apu[3] = lo[3];
            apu[4] = hi[0]; apu[5] = hi[1]; apu[6] = hi[2]; apu[7] = hi[3];
            bfrag ap = __builtin_bit_cast(bfrag, apu);
#pragma unroll
            for (int oc = 0; oc < 4; oc++) {
                bfrag bv = *(const bfrag*)&Vt[(oc * 16 + l15) * LPV + kk * 32 + quad * 8];
                accO[oc] = __builtin_amdgcn_mfma_f32_16x16x32_bf16(ap, bv, accO[oc], 0, 0, 0);
            }
        }
    }

    // epilogue: reduce l over the 16 row-lanes, normalize, store
#pragma unroll
    for (int r = 0; r < 4; r++) {
        float l = l_run[r];
#pragma unroll
        for (int m = 1; m < 16; m <<= 1) l += __shfl_xor(l, m);
        float linv = 1.0f / l;
        int srow = qt * 64 + wave * 16 + quad * 4 + r;
#pragma unroll
        for (int oc = 0; oc < 4; oc++)
            o[(size_t)(b * 1024 + srow) * 1024 + h * 64 + oc * 16 + l15] =
                f2bf(accO[oc][r] * linv);
    }
}

// ---------------------------------------------------------------------------
extern "C" void kernel_launch(void* const* d_in, const int* in_sizes, int n_in,
                              void* d_out, int out_size, void* d_ws, size_t ws_size,
                              hipStream_t stream) {
    const float* x     = (const float*)d_in[0];
    const float* ln1_s = (const float*)d_in[2];
    const float* ln1_b = (const float*)d_in[3];
    const float* Wq = (const float*)d_in[4];  const float* bq = (const float*)d_in[5];
    const float* Wk = (const float*)d_in[6];  const float* bk = (const float*)d_in[7];
    const float* Wv = (const float*)d_in[8];  const float* bv = (const float*)d_in[9];
    const float* qn_s = (const float*)d_in[10]; const float* qn_b = (const float*)d_in[11];
    const float* kn_s = (const float*)d_in[12]; const float* kn_b = (const float*)d_in[13];
    const float* Wo = (const float*)d_in[14]; const float* bo = (const float*)d_in[15];
    const float* ln2_s = (const float*)d_in[16]; const float* ln2_b = (const float*)d_in[17];
    const float* W1 = (const float*)d_in[18]; const float* b1 = (const float*)d_in[19];
    const float* W2 = (const float*)d_in[20]; const float* b2 = (const float*)d_in[21];
    const float* W3 = (const float*)d_in[22]; const float* b3 = (const float*)d_in[23];
    float* out = (float*)d_out;

    char* ws = (char*)d_ws;
    const size_t MB = (size_t)1 << 20;
    u16* WqkvT = (u16*)(ws + 0);         // 0..6    dead after QKV; then p0 @0
    u16* WoT   = (u16*)(ws + 6 * MB);    // 6..8    dead after Wo
    u16* W12T  = (u16*)(ws + 8 * MB);    // 8..24   dead after W12; then p1/p2
    u16* W3T   = (u16*)(ws + 24 * MB);   // 24..32  dead after splitk
    u16* xn1   = (u16*)(ws + 32 * MB);   // 32..40  dead after QKV
    u16* attn  = (u16*)(ws + 32 * MB);   //   reuse: dead after Wo-gemm
    u16* xn2   = (u16*)(ws + 32 * MB);   //   reuse: dead after W12
    u16* qkv   = (u16*)(ws + 40 * MB);   // 40..64  dead after flash
    float* xmid = (float*)(ws + 40 * MB);//   reuse: 40..56, alive until reduce4
    u16* p3    = (u16*)(ws + 56 * MB);   // 56..64
    u16* h     = (u16*)(ws + 64 * MB);   // 64..96  dead after splitk
    u16* wp0   = (u16*)(ws + 64 * MB);   // Wo partials: 64..72, 72..80
    u16* wp1   = (u16*)(ws + 72 * MB);   //   dead after reduce_ln (before h)
    u16* p0    = (u16*)(ws + 0);
    u16* p1    = (u16*)(ws + 8 * MB);
    u16* p2    = (u16*)(ws + 16 * MB);
    // peak = 96 MB

    wtln<<<20480, 256, 0, stream>>>(Wq, Wk, Wv, Wo, W1, W2, W3,
                                    WqkvT, WoT, W12T, W3T,
                                    x, ln1_s, ln1_b, xn1);

    // fused QKV + per-head QK-norm (BK=64)
    gemm64<4><<<dim3(24, 32, 1), 256, 0, stream>>>(
        xn1, WqkvT, bq, bk, bv, qn_s, qn_b, kn_s, kn_b,
        qkv, nullptr, nullptr, nullptr, 4096, 3072, 1024, 1024);

    flash<<<dim3(16, 16, 4), 256, 0, stream>>>(qkv, attn);

    // Wo split-K=2 partials (BK=64)
    gemm64<0><<<dim3(8, 32, 2), 256, 0, stream>>>(
        attn, WoT, nullptr, nullptr, nullptr, nullptr, nullptr, nullptr, nullptr,
        wp0, wp1, nullptr, nullptr, 4096, 1024, 1024, 512);

    // xmid = x + bo + wp0 + wp1; xn2 = LN2(xmid)
    reduce_ln<<<4096, 256, 0, stream>>>(wp0, wp1, x, bo, ln2_s, ln2_b, xmid, xn2);

    // fused GeGLU FFN (BK=64)
    gemm_w12<<<dim3(32, 32), 256, 0, stream>>>(xn2, W12T, b1, b2, h);

    // W3 split-K=4 partials (BK=64)
    gemm64<0><<<dim3(8, 32, 4), 256, 0, stream>>>(
        h, W3T, nullptr, nullptr, nullptr, nullptr, nullptr, nullptr, nullptr,
        p0, p1, p2, p3, 4096, 1024, 4096, 1024);

    // out = xmid + b3 + sum(partials)
    reduce4<<<4096, 256, 0, stream>>>(p0, p1, p2, p3, xmid, b3, out);
}